// Round 1
// baseline (154.429 us; speedup 1.0000x reference)
//
#include <hip/hip_runtime.h>

// x: (32, 3, 512, 512) fp32, channel plane stride HW = 512*512 = 262144.
// out: (32, 1, 512, 512) fp32.
// Memory-bound elementwise: 1 thread = 4 pixels (float4), coalesced.

#define HW    262144          // 512*512
#define NPIX  8388608         // 32*HW (output elements)

__global__ __launch_bounds__(256) void HBEMD_F_67156108640795_kernel(
    const float* __restrict__ x,
    const float* __restrict__ Wp,
    const float* __restrict__ Bp,
    float* __restrict__ out)
{
    int v = blockIdx.x * blockDim.x + threadIdx.x;   // float4 index
    int o = v << 2;                                  // pixel index
    if (o >= NPIX) return;

    int n = o >> 18;                                 // o / HW
    int p = o & (HW - 1);                            // o % HW
    const float* base = x + (size_t)n * (3 * HW) + p;

    float4 r4 = *(const float4*)(base);
    float4 g4 = *(const float4*)(base + HW);
    float4 b4 = *(const float4*)(base + 2 * HW);

    float w  = Wp[0];
    float bb = Bp[0];

    float rr[4] = {r4.x, r4.y, r4.z, r4.w};
    float gg[4] = {g4.x, g4.y, g4.z, g4.w};
    float bl[4] = {b4.x, b4.y, b4.z, b4.w};
    float oo[4];

#pragma unroll
    for (int k = 0; k < 4; ++k) {
        float r = rr[k], g = gg[k], b = bl[k];
        float cmax  = fmaxf(r, fmaxf(g, b));
        float cmin  = fminf(r, fminf(g, b));
        float delta = cmax - cmin;

        // safe reciprocal (delta==0 lanes select hue=0 below anyway)
        float sd  = (delta == 0.0f) ? 1.0f : delta;
        float inv = 1.0f / sd;

        // h0 = mod((g-b)/d, 6)  -- t in [-1,1] when selected, so t<0 ? t+6 : t
        float t0 = (g - b) * inv;
        t0 = (t0 < 0.0f) ? (t0 + 6.0f) : t0;
        float t1 = (b - r) * inv + 2.0f;
        float t2 = (r - g) * inv + 4.0f;

        // argmax first-occurrence: 0 if r==cmax, else 1 if g==cmax, else 2.
        float hue = (r == cmax) ? t0 : ((g == cmax) ? t1 : t2);
        hue = (delta == 0.0f) ? 0.0f : hue;

        oo[k] = (hue / 6.0f) * w + bb;
    }

    float4 o4 = make_float4(oo[0], oo[1], oo[2], oo[3]);
    *(float4*)(out + o) = o4;
}

extern "C" void kernel_launch(void* const* d_in, const int* in_sizes, int n_in,
                              void* d_out, int out_size, void* d_ws, size_t ws_size,
                              hipStream_t stream) {
    const float* x  = (const float*)d_in[0];
    const float* W  = (const float*)d_in[1];
    const float* b  = (const float*)d_in[2];
    float* out = (float*)d_out;

    const int threads = 256;
    const int nvec = NPIX / 4;                 // 2,097,152
    const int blocks = nvec / threads;         // 8192 exactly
    HBEMD_F_67156108640795_kernel<<<blocks, threads, 0, stream>>>(x, W, b, out);
}